// Round 2
// 513.190 us; speedup vs baseline: 1.0621x; 1.0621x over previous
//
#include <hip/hip_runtime.h>
#include <stdint.h>
#include <stddef.h>

typedef __bf16 bf16_t;
typedef __bf16 bf16x4 __attribute__((ext_vector_type(4)));
typedef __bf16 bf16x8 __attribute__((ext_vector_type(8)));
typedef float  f32x4  __attribute__((ext_vector_type(4)));

#define H_   12
#define N_   49
#define C_   384
#define D_   32
#define NW_  64
#define C3_  1152

// ---- LDS layout (bytes) ----
// region 0: xs (phase1/2: 49 x 392 bf16) / per-wave P buffers (phase 3)
// region 1: q  (phase3: 49 x 392 bf16, [tok][dim]) / ao (phase 4)
// region 2: k  (phase3: 49 x 392 bf16, [tok][dim])
// region 3: vT (phase3: 384 x 56 bf16, [dim][tok]) + 32B read guard
#define XS_STRIDE 392
#define Q_OFF     38416
#define K_OFF     76832
#define VT_OFF    115248
#define VT_STRIDE 56
#define P_STRIDE  72            // elems; per-wave P: 16 rows x 144B = 2304 B
#define SMEM_BYTES 158288       // 115248 + 384*112 + 32 guard

#define WQKV_ELEMS  (C3_ * C_)   // 442368
#define WPROJ_ELEMS (C_ * C_)    // 147456

// ---------------------------------------------------------------------------
// prep_w: coalesced frag-order transpose of both weight matrices.
// out[((ct*12+ks)*64+lane)*8 + j] = W[ks*32+(lane>>4)*8+j][ct*16+(lane&15)]
// ---------------------------------------------------------------------------
__global__ void prep_w(const float* __restrict__ qkv_w,
                       const float* __restrict__ proj_w,
                       bf16_t* __restrict__ wqkvT,
                       bf16_t* __restrict__ wprojT)
{
    __shared__ bf16_t tile[32][72];
    int bid = blockIdx.x;
    const float* src; bf16_t* dst; int NC, ks, g;
    if (bid < 216) { src = qkv_w;  dst = wqkvT;  NC = C3_; ks = bid % 12; g = bid / 12; }
    else { bid -= 216; src = proj_w; dst = wprojT; NC = C_;  ks = bid % 12; g = bid / 12; }
    const int n0 = g * 64;
    const int t = threadIdx.x;
    const int r0 = t >> 6, cc = t & 63;
    #pragma unroll
    for (int p = 0; p < 8; ++p) {
        int row = p * 4 + r0;
        tile[row][cc] = (bf16_t)src[(ks * 32 + row) * NC + n0 + cc];
    }
    __syncthreads();
    const int lane = t & 63, ctl = t >> 6;
    const int q4 = lane >> 4, l15 = lane & 15;
    bf16x8 v;
    #pragma unroll
    for (int j = 0; j < 8; ++j) v[j] = tile[q4 * 8 + j][ctl * 16 + l15];
    *(bf16x8*)(dst + ((size_t)((g * 4 + ctl) * 12 + ks) * 64 + lane) * 8) = v;
}

// ---------------------------------------------------------------------------
// prep_bias: T[w][h][m][n] = (rpb[h][m][n] + mask[w][m][n]) * log2(e), bf16.
// n padded to 64 (zeros). One block per (w,h).
// ---------------------------------------------------------------------------
__global__ void prep_bias(const float* __restrict__ mask,
                          const float* __restrict__ rpb,
                          bf16_t* __restrict__ T)
{
    const int w = blockIdx.x / H_, h = blockIdx.x % H_;
    bf16_t* out = T + (size_t)(w * H_ + h) * (N_ * 64);
    for (int idx = threadIdx.x; idx < N_ * 64; idx += 256) {
        int m = idx >> 6, n = idx & 63;
        float v = 0.f;
        if (n < N_)
            v = (rpb[(h * N_ + m) * N_ + n] + mask[((size_t)w * N_ + m) * N_ + n])
                * 1.4426950408889634f;
        out[idx] = (bf16_t)v;
    }
}

// ---------------------------------------------------------------------------
// Fused per-window kernel: one block per window b, 12 waves (768 threads).
// Work split so every phase divides by 12 with NO duplicated weight reads:
//   phase 2: 72 column-tiles -> 6/wave (waves 0..7 A-type q/k, 8..11 B-type v)
//   phase 3: wave = head (12 heads), 4 query row-tiles each; K/V frags
//            loaded once per wave and reused across the 4 tiles
//   phase 4: 24 column-tiles -> 2/wave
// LDS unchanged (158.7 KB, 1 block/CU) but occupancy 8 -> 12 waves/CU.
// ---------------------------------------------------------------------------
__global__ __launch_bounds__(768, 3)
void fused_window_attn(const float* __restrict__ x,
                       const float* __restrict__ qkv_b,
                       const float* __restrict__ proj_b,
                       const bf16_t* __restrict__ wqkvT,
                       const bf16_t* __restrict__ wprojT,
                       const bf16_t* __restrict__ btbl,
                       float* __restrict__ out)
{
    __shared__ __align__(16) unsigned char smem[SMEM_BYTES];
    bf16_t* xs = (bf16_t*)smem;                 // phase 1/2
    bf16_t* qa = (bf16_t*)(smem + Q_OFF);       // q [tok][dim], later ao
    bf16_t* ka = (bf16_t*)(smem + K_OFF);       // k [tok][dim]
    bf16_t* vt = (bf16_t*)(smem + VT_OFF);      // v^T [dim][tok]

    const int tid  = threadIdx.x;
    const int wave = tid >> 6;                  // 0..11
    const int lane = tid & 63;
    const int q4   = lane >> 4;
    const int l15  = lane & 15;
    const int b    = blockIdx.x;

    const f32x4 z4 = {0.f, 0.f, 0.f, 0.f};

    // ---------------- phase 1: x[b] -> bf16 LDS; zero vt padding ----------
    {
        // Zero vt token-columns 48..55 of every row + the 32B tail guard.
        // Tokens 49..55 are never written by phase 2 but ARE read (x P==0)
        // by the PV b128 fragments: 0*NaN = NaN, so they must be real zeros.
        for (int t = tid; t < 384 * 8; t += 768) {
            int r = t >> 3, c = t & 7;
            vt[r * VT_STRIDE + 48 + c] = (bf16_t)0.f;
        }
        if (tid < 16) vt[384 * VT_STRIDE + tid] = (bf16_t)0.f;

        const float* xg = x + (size_t)b * (N_ * C_);
        for (int t = tid; t < (N_ * C_) / 4; t += 768) {
            float4 v = ((const float4*)xg)[t];
            int r = t / 96, c4 = t % 96;
            bf16x4 o;
            o[0] = (bf16_t)v.x; o[1] = (bf16_t)v.y;
            o[2] = (bf16_t)v.z; o[3] = (bf16_t)v.w;
            *(bf16x4*)(xs + r * XS_STRIDE + c4 * 4) = o;
        }
    }
    __syncthreads();

    // ---------------- phase 2: qkv GEMM, 6 column-tiles per wave ----------
    // waves 0..7:  A-type (swapped operands), q+k cols, ct = wave*6 .. +5
    // waves 8..11: B-type (normal), v cols, ct = 48 + (wave-8)*6 .. +5
    if (wave < 8) {
        const int tbase = wave * 6;
        f32x4 acc[6][4];
        #pragma unroll
        for (int jj = 0; jj < 6; ++jj)
            #pragma unroll
            for (int mi = 0; mi < 4; ++mi) acc[jj][mi] = z4;

        for (int ks = 0; ks < 12; ++ks) {
            bf16x8 xf[4];
            #pragma unroll
            for (int mi = 0; mi < 4; ++mi)
                xf[mi] = *(const bf16x8*)(xs + (mi * 16 + l15) * XS_STRIDE + ks * 32 + q4 * 8);
            #pragma unroll
            for (int jj = 0; jj < 6; ++jj) {
                bf16x8 wf = *(const bf16x8*)(wqkvT +
                    ((size_t)((tbase + jj) * 12 + ks) * 64 + lane) * 8);
                #pragma unroll
                for (int mi = 0; mi < 4; ++mi)
                    acc[jj][mi] = __builtin_amdgcn_mfma_f32_16x16x32_bf16(
                        wf, xf[mi], acc[jj][mi], 0, 0, 0);
            }
        }
        // epilogue A: C-layout (chan=ct*16+q4*4+r, tok=l15) -> q/k [tok][chan]
        #pragma unroll
        for (int jj = 0; jj < 6; ++jj) {
            const int ct = tbase + jj;
            const int c0 = ct * 16 + q4 * 4;
            float4 bv = *(const float4*)(qkv_b + c0);
            bf16_t* dst = (ct < 24) ? qa : ka;
            const int cc = c0 - (ct < 24 ? 0 : C_);
            #pragma unroll
            for (int mi = 0; mi < 4; ++mi) {
                const int m = mi * 16 + l15;
                if (m < N_) {
                    bf16x4 o;
                    o[0] = (bf16_t)(acc[jj][mi][0] + bv.x);
                    o[1] = (bf16_t)(acc[jj][mi][1] + bv.y);
                    o[2] = (bf16_t)(acc[jj][mi][2] + bv.z);
                    o[3] = (bf16_t)(acc[jj][mi][3] + bv.w);
                    *(bf16x4*)(dst + m * XS_STRIDE + cc) = o;
                }
            }
        }
    } else {
        const int tbase = 48 + (wave - 8) * 6;
        f32x4 acc[6][4];
        #pragma unroll
        for (int jj = 0; jj < 6; ++jj)
            #pragma unroll
            for (int mi = 0; mi < 4; ++mi) acc[jj][mi] = z4;

        for (int ks = 0; ks < 12; ++ks) {
            bf16x8 xf[4];
            #pragma unroll
            for (int mi = 0; mi < 4; ++mi)
                xf[mi] = *(const bf16x8*)(xs + (mi * 16 + l15) * XS_STRIDE + ks * 32 + q4 * 8);
            #pragma unroll
            for (int jj = 0; jj < 6; ++jj) {
                bf16x8 wf = *(const bf16x8*)(wqkvT +
                    ((size_t)((tbase + jj) * 12 + ks) * 64 + lane) * 8);
                #pragma unroll
                for (int mi = 0; mi < 4; ++mi)
                    acc[jj][mi] = __builtin_amdgcn_mfma_f32_16x16x32_bf16(
                        xf[mi], wf, acc[jj][mi], 0, 0, 0);
            }
        }
        // epilogue B: C-layout (tok=q4*4+r+mi*16, chan=ct*16+l15) -> vT [dim][tok]
        #pragma unroll
        for (int jj = 0; jj < 6; ++jj) {
            const int ct = tbase + jj;       // 48..71
            const int c  = ct * 16 + l15;
            const int d  = c - 2 * C_;       // v dim 0..383
            const float bb = qkv_b[c];
            #pragma unroll
            for (int mi = 0; mi < 4; ++mi) {
                const int t0 = mi * 16 + q4 * 4;
                if (t0 + 3 < N_) {
                    bf16x4 o;
                    #pragma unroll
                    for (int r = 0; r < 4; ++r) o[r] = (bf16_t)(acc[jj][mi][r] + bb);
                    *(bf16x4*)(vt + d * VT_STRIDE + t0) = o;
                } else {
                    #pragma unroll
                    for (int r = 0; r < 4; ++r)
                        if (t0 + r < N_)
                            vt[d * VT_STRIDE + t0 + r] = (bf16_t)(acc[jj][mi][r] + bb);
                }
            }
        }
    }
    __syncthreads();

    // ---------------- phase 3: attention, wave = head, 4 row-tiles --------
    f32x4 oak[4][2];
    {
        bf16_t* pb = (bf16_t*)(smem + wave * 2304);   // 16 x 72 bf16 (xs dead)
        const bf16_t* tb = btbl + (size_t)((b & (NW_ - 1)) * H_ + wave) * (N_ * 64);
        const float SC = 0.17677669529663687f * 1.4426950408889634f;

        // K and V fragments for this head: loaded once, reused for all 4 mt
        bf16x8 kf[4];
        #pragma unroll
        for (int ni = 0; ni < 4; ++ni)
            kf[ni] = *(const bf16x8*)(ka + (ni * 16 + l15) * XS_STRIDE
                                         + wave * D_ + q4 * 8);
        bf16x8 vf[2][2];
        #pragma unroll
        for (int ks2 = 0; ks2 < 2; ++ks2)
            #pragma unroll
            for (int dt = 0; dt < 2; ++dt)
                vf[ks2][dt] = *(const bf16x8*)(vt + (wave * D_ + dt * 16 + l15) * VT_STRIDE
                                                  + ks2 * 32 + q4 * 8);

        #pragma unroll
        for (int mt = 0; mt < 4; ++mt) {
            bf16x8 qf = *(const bf16x8*)(qa + (mt * 16 + l15) * XS_STRIDE
                                            + wave * D_ + q4 * 8);
            // S^T[n][m]
            f32x4 sacc[4];
            #pragma unroll
            for (int ni = 0; ni < 4; ++ni)
                sacc[ni] = __builtin_amdgcn_mfma_f32_16x16x32_bf16(
                    kf[ni], qf, z4, 0, 0, 0);

            // bias + exp2 + row sum (lane's m = mt*16+l15)
            const int m  = mt * 16 + l15;
            const int mc = m < 48 ? m : 48;
            float den = 0.f;
            #pragma unroll
            for (int ni = 0; ni < 4; ++ni) {
                bf16x4 bv = *(const bf16x4*)(tb + (size_t)mc * 64 + ni * 16 + q4 * 4);
                #pragma unroll
                for (int r = 0; r < 4; ++r) {
                    const int n = ni * 16 + q4 * 4 + r;
                    float s = 0.f;
                    if (n < N_)
                        s = __builtin_exp2f(sacc[ni][r] * SC + (float)bv[r]);
                    sacc[ni][r] = s;
                    den += s;
                }
            }
            den += __shfl_xor(den, 16);
            den += __shfl_xor(den, 32);
            const float ri = __builtin_amdgcn_rcpf(den);

            // P[m][n] b64 writes (exact zeros for n>=49; rows m>=49 skipped:
            // stale finite data from previous mt, masked at staging)
            if (m < N_) {
                #pragma unroll
                for (int ni = 0; ni < 4; ++ni) {
                    bf16x4 o;
                    #pragma unroll
                    for (int r = 0; r < 4; ++r) o[r] = (bf16_t)(sacc[ni][r] * ri);
                    *(bf16x4*)(pb + l15 * P_STRIDE + ni * 16 + q4 * 4) = o;
                }
            }

            // out = P @ V
            oak[mt][0] = z4; oak[mt][1] = z4;
            #pragma unroll
            for (int ks2 = 0; ks2 < 2; ++ks2) {
                bf16x8 pf = *(const bf16x8*)(pb + l15 * P_STRIDE + ks2 * 32 + q4 * 8);
                #pragma unroll
                for (int dt = 0; dt < 2; ++dt)
                    oak[mt][dt] = __builtin_amdgcn_mfma_f32_16x16x32_bf16(
                        pf, vf[ks2][dt], oak[mt][dt], 0, 0, 0);
            }
        }
    }
    __syncthreads();   // all q reads done before ao overwrites region 1

    // stage attn_out into region 1 (C-layout: m=q4*4+r, dcol=l15)
    {
        #pragma unroll
        for (int mt = 0; mt < 4; ++mt)
            #pragma unroll
            for (int dt = 0; dt < 2; ++dt) {
                const int c = wave * D_ + dt * 16 + l15;
                #pragma unroll
                for (int r = 0; r < 4; ++r) {
                    const int m = mt * 16 + q4 * 4 + r;
                    if (m < N_) qa[m * XS_STRIDE + c] = (bf16_t)oak[mt][dt][r];
                }
            }
    }
    __syncthreads();

    // ---------------- phase 4: out = ao @ Wproj + b, 2 tiles/wave ---------
    {
        f32x4 pacc[2][4];
        #pragma unroll
        for (int jj = 0; jj < 2; ++jj)
            #pragma unroll
            for (int mi = 0; mi < 4; ++mi) pacc[jj][mi] = z4;

        for (int ks = 0; ks < 12; ++ks) {
            bf16x8 af[4];
            #pragma unroll
            for (int mi = 0; mi < 4; ++mi)
                af[mi] = *(const bf16x8*)(qa + (mi * 16 + l15) * XS_STRIDE + ks * 32 + q4 * 8);
            #pragma unroll
            for (int jj = 0; jj < 2; ++jj) {
                bf16x8 wf = *(const bf16x8*)(wprojT +
                    ((size_t)((wave * 2 + jj) * 12 + ks) * 64 + lane) * 8);
                #pragma unroll
                for (int mi = 0; mi < 4; ++mi)
                    pacc[jj][mi] = __builtin_amdgcn_mfma_f32_16x16x32_bf16(
                        af[mi], wf, pacc[jj][mi], 0, 0, 0);
            }
        }
        float* og = out + (size_t)b * (N_ * C_);
        #pragma unroll
        for (int jj = 0; jj < 2; ++jj) {
            const int n = (wave * 2 + jj) * 16 + l15;
            const float bias = proj_b[n];
            #pragma unroll
            for (int mi = 0; mi < 4; ++mi) {
                #pragma unroll
                for (int r = 0; r < 4; ++r) {
                    const int m = mi * 16 + q4 * 4 + r;
                    if (m < N_) og[m * C_ + n] = pacc[jj][mi][r] + bias;
                }
            }
        }
    }
}

// ---------------------------------------------------------------------------
extern "C" void kernel_launch(void* const* d_in, const int* in_sizes, int n_in,
                              void* d_out, int out_size, void* d_ws, size_t ws_size,
                              hipStream_t stream)
{
    const float* x      = (const float*)d_in[0];
    const float* mask   = (const float*)d_in[1];
    const float* qkv_w  = (const float*)d_in[2];
    const float* qkv_b  = (const float*)d_in[3];
    const float* proj_w = (const float*)d_in[4];
    const float* proj_b = (const float*)d_in[5];
    const float* rpb    = (const float*)d_in[6];
    float* out = (float*)d_out;

    bf16_t* wqkvT  = (bf16_t*)d_ws;
    bf16_t* wprojT = wqkvT + WQKV_ELEMS;
    bf16_t* btbl   = wprojT + WPROJ_ELEMS;   // 64*12*49*64 bf16 = 4.8 MB

    prep_w<<<288, 256, 0, stream>>>(qkv_w, proj_w, wqkvT, wprojT);
    prep_bias<<<NW_ * H_, 256, 0, stream>>>(mask, rpb, btbl);
    fused_window_attn<<<2048, 768, 0, stream>>>(x, qkv_b, proj_b,
                                                wqkvT, wprojT, btbl, out);
}